// Round 1
// baseline (1209.481 us; speedup 1.0000x reference)
//
#include <hip/hip_runtime.h>
#include <cfloat>
#include <cstddef>

#define BATCH 8
#define CDIM  256
#define NTOK  2304   // 48*48

// ---------------------------------------------------------------------------
// Projection: OUT[o,n] = sum_c W[o,c] * X[b,c,n] + bias[o]
// mode 0: Q from x1 -> layout [B,N,C]
// mode 1: K from x2 -> layout [B,C,N]
// mode 2: V from x2 -> layout [B,N,C]
// Block 256 threads, tile 64 o x 64 n, K-chunks of 16.
// ---------------------------------------------------------------------------
__global__ __launch_bounds__(256) void proj_kernel(
    const float* __restrict__ x1, const float* __restrict__ x2,
    const float* __restrict__ Wq, const float* __restrict__ bq,
    const float* __restrict__ Wk, const float* __restrict__ bk,
    const float* __restrict__ Wv, const float* __restrict__ bv,
    float* __restrict__ Qo, float* __restrict__ Ko, float* __restrict__ Vo)
{
    const int tid = threadIdx.x;
    const int tx = tid & 15, ty = tid >> 4;
    const int n0 = blockIdx.x * 64;
    const int o0 = blockIdx.y * 64;
    const int bz = blockIdx.z;
    const int b = bz / 3, mode = bz % 3;

    const float* X    = (mode == 0) ? x1 : x2;
    const float* W    = (mode == 0) ? Wq : (mode == 1) ? Wk : Wv;
    const float* bias = (mode == 0) ? bq : (mode == 1) ? bk : bv;
    float*       OUT  = (mode == 0) ? Qo : (mode == 1) ? Ko : Vo;

    __shared__ float Ws[16][68];  // [kc][o], padded to dodge store conflicts
    __shared__ float Xs[16][64];  // [kc][n]

    float acc[4][4];
#pragma unroll
    for (int i = 0; i < 4; ++i)
#pragma unroll
        for (int j = 0; j < 4; ++j) acc[i][j] = 0.f;

    for (int c0 = 0; c0 < CDIM; c0 += 16) {
        __syncthreads();
#pragma unroll
        for (int it = 0; it < 4; ++it) {
            int e = tid + it * 256;
            Ws[e & 15][e >> 4] = W[(o0 + (e >> 4)) * CDIM + c0 + (e & 15)];
        }
#pragma unroll
        for (int it = 0; it < 4; ++it) {
            int e = tid + it * 256;
            Xs[e >> 6][e & 63] =
                X[(size_t)(b * CDIM + c0 + (e >> 6)) * NTOK + n0 + (e & 63)];
        }
        __syncthreads();
#pragma unroll
        for (int kc = 0; kc < 16; ++kc) {
            float4 a  = *(const float4*)&Ws[kc][ty * 4];
            float4 xv = *(const float4*)&Xs[kc][tx * 4];
            acc[0][0] = fmaf(a.x, xv.x, acc[0][0]);
            acc[0][1] = fmaf(a.x, xv.y, acc[0][1]);
            acc[0][2] = fmaf(a.x, xv.z, acc[0][2]);
            acc[0][3] = fmaf(a.x, xv.w, acc[0][3]);
            acc[1][0] = fmaf(a.y, xv.x, acc[1][0]);
            acc[1][1] = fmaf(a.y, xv.y, acc[1][1]);
            acc[1][2] = fmaf(a.y, xv.z, acc[1][2]);
            acc[1][3] = fmaf(a.y, xv.w, acc[1][3]);
            acc[2][0] = fmaf(a.z, xv.x, acc[2][0]);
            acc[2][1] = fmaf(a.z, xv.y, acc[2][1]);
            acc[2][2] = fmaf(a.z, xv.z, acc[2][2]);
            acc[2][3] = fmaf(a.z, xv.w, acc[2][3]);
            acc[3][0] = fmaf(a.w, xv.x, acc[3][0]);
            acc[3][1] = fmaf(a.w, xv.y, acc[3][1]);
            acc[3][2] = fmaf(a.w, xv.z, acc[3][2]);
            acc[3][3] = fmaf(a.w, xv.w, acc[3][3]);
        }
    }

    if (mode == 1) {
        // direct layout [B, C, N]
#pragma unroll
        for (int i = 0; i < 4; ++i) {
            float bb = bias[o0 + ty * 4 + i];
            float4 v = make_float4(acc[i][0] + bb, acc[i][1] + bb,
                                   acc[i][2] + bb, acc[i][3] + bb);
            *(float4*)&OUT[(size_t)(b * CDIM + o0 + ty * 4 + i) * NTOK + n0 + tx * 4] = v;
        }
    } else {
        // transposed layout [B, N, C]
        float b0 = bias[o0 + ty * 4 + 0];
        float b1 = bias[o0 + ty * 4 + 1];
        float b2 = bias[o0 + ty * 4 + 2];
        float b3 = bias[o0 + ty * 4 + 3];
#pragma unroll
        for (int j = 0; j < 4; ++j) {
            float4 v = make_float4(acc[0][j] + b0, acc[1][j] + b1,
                                   acc[2][j] + b2, acc[3][j] + b3);
            *(float4*)&OUT[(size_t)(b * NTOK + n0 + tx * 4 + j) * CDIM + o0 + ty * 4] = v;
        }
    }
}

// ---------------------------------------------------------------------------
// Flash-style attention, fp32. Block = 256 threads, 32 query rows per block.
// Q: [B,N,C], K: [B,C,N], V: [B,N,C], out: [B,C,N]
// ---------------------------------------------------------------------------
__global__ __launch_bounds__(256) void attn_kernel(
    const float* __restrict__ Q, const float* __restrict__ Kd,
    const float* __restrict__ V, float* __restrict__ out)
{
    const int tid = threadIdx.x;
    const int b  = blockIdx.y;
    const int n0 = blockIdx.x * 32;

    __shared__ float Qs[32][260];   // Q tile; reused to stage output
    __shared__ float Ss[32][68];    // score / prob tile
    __shared__ float mrow[32], lrow[32], srow[32];

    // load Q tile: 32 rows x 256 cols as float4 (coalesced)
#pragma unroll
    for (int it = 0; it < 8; ++it) {
        int f = tid + it * 256;      // float4 index
        int r = f >> 6, c4 = f & 63;
        *(float4*)&Qs[r][c4 * 4] =
            *(const float4*)&Q[((size_t)b * NTOK + n0 + r) * CDIM + c4 * 4];
    }
    if (tid < 32) { mrow[tid] = -FLT_MAX; lrow[tid] = 0.f; }

    const int jtx = tid & 63, jty = tid >> 6;   // QK phase: j-lane, row group
    const int ctx = tid & 63, cty = tid >> 6;   // PV phase: c-lane, row group

    float4 acc[8];
#pragma unroll
    for (int rr = 0; rr < 8; ++rr) acc[rr] = make_float4(0.f, 0.f, 0.f, 0.f);

    __syncthreads();

    for (int j0 = 0; j0 < NTOK; j0 += 64) {
        // ---------------- QK^T: S[32][64] ----------------
        float s[8];
#pragma unroll
        for (int rr = 0; rr < 8; ++rr) s[rr] = 0.f;
        for (int c0 = 0; c0 < CDIM; c0 += 4) {
            float kv0 = Kd[(size_t)(b * CDIM + c0 + 0) * NTOK + j0 + jtx];
            float kv1 = Kd[(size_t)(b * CDIM + c0 + 1) * NTOK + j0 + jtx];
            float kv2 = Kd[(size_t)(b * CDIM + c0 + 2) * NTOK + j0 + jtx];
            float kv3 = Kd[(size_t)(b * CDIM + c0 + 3) * NTOK + j0 + jtx];
#pragma unroll
            for (int rr = 0; rr < 8; ++rr) {
                float4 q = *(const float4*)&Qs[jty * 8 + rr][c0];
                s[rr] = fmaf(q.x, kv0, s[rr]);
                s[rr] = fmaf(q.y, kv1, s[rr]);
                s[rr] = fmaf(q.z, kv2, s[rr]);
                s[rr] = fmaf(q.w, kv3, s[rr]);
            }
        }
#pragma unroll
        for (int rr = 0; rr < 8; ++rr) Ss[jty * 8 + rr][jtx] = s[rr];
        __syncthreads();

        // ---------------- online softmax ----------------
        {
            int r = tid >> 3, g = tid & 7;      // 8 threads per row
            float lm = -FLT_MAX;
#pragma unroll
            for (int u = 0; u < 8; ++u) lm = fmaxf(lm, Ss[r][g * 8 + u]);
            lm = fmaxf(lm, __shfl_xor(lm, 1));
            lm = fmaxf(lm, __shfl_xor(lm, 2));
            lm = fmaxf(lm, __shfl_xor(lm, 4));
            float mnew = fmaxf(mrow[r], lm);
            float lsum = 0.f;
#pragma unroll
            for (int u = 0; u < 8; ++u) {
                float p = __expf(Ss[r][g * 8 + u] - mnew);
                Ss[r][g * 8 + u] = p;
                lsum += p;
            }
            lsum += __shfl_xor(lsum, 1);
            lsum += __shfl_xor(lsum, 2);
            lsum += __shfl_xor(lsum, 4);
            if (g == 0) {
                float sc = __expf(mrow[r] - mnew);
                srow[r] = sc;
                lrow[r] = lrow[r] * sc + lsum;
                mrow[r] = mnew;
            }
        }
        __syncthreads();

        // ---------------- PV accumulate ----------------
#pragma unroll
        for (int rr = 0; rr < 8; ++rr) {
            float sc = srow[cty * 8 + rr];
            acc[rr].x *= sc; acc[rr].y *= sc; acc[rr].z *= sc; acc[rr].w *= sc;
        }
        for (int jj = 0; jj < 64; jj += 4) {
            float4 p4[8];
#pragma unroll
            for (int rr = 0; rr < 8; ++rr)
                p4[rr] = *(const float4*)&Ss[cty * 8 + rr][jj];
#pragma unroll
            for (int u = 0; u < 4; ++u) {
                float4 vv = *(const float4*)&V[((size_t)b * NTOK + j0 + jj + u) * CDIM + ctx * 4];
#pragma unroll
                for (int rr = 0; rr < 8; ++rr) {
                    float p = (u == 0) ? p4[rr].x : (u == 1) ? p4[rr].y
                             : (u == 2) ? p4[rr].z : p4[rr].w;
                    acc[rr].x = fmaf(p, vv.x, acc[rr].x);
                    acc[rr].y = fmaf(p, vv.y, acc[rr].y);
                    acc[rr].z = fmaf(p, vv.z, acc[rr].z);
                    acc[rr].w = fmaf(p, vv.w, acc[rr].w);
                }
            }
        }
        __syncthreads();   // protect Ss/srow before next iteration overwrites
    }

    // ---------------- epilogue: normalize, transpose via LDS, write [B,C,N] ----
#pragma unroll
    for (int rr = 0; rr < 8; ++rr) {
        float inv = 1.f / lrow[cty * 8 + rr];
        float4 v = acc[rr];
        v.x *= inv; v.y *= inv; v.z *= inv; v.w *= inv;
        *(float4*)&Qs[cty * 8 + rr][ctx * 4] = v;
    }
    __syncthreads();
    {
        int r = tid & 31, cg = tid >> 5;
        for (int c = cg; c < CDIM; c += 8)
            out[((size_t)b * CDIM + c) * NTOK + n0 + r] = Qs[r][c];
    }
}

// ---------------------------------------------------------------------------
extern "C" void kernel_launch(void* const* d_in, const int* in_sizes, int n_in,
                              void* d_out, int out_size, void* d_ws, size_t ws_size,
                              hipStream_t stream)
{
    const float* x1 = (const float*)d_in[0];
    const float* x2 = (const float*)d_in[1];
    const float* Wq = (const float*)d_in[2];
    const float* bq = (const float*)d_in[3];
    const float* Wk = (const float*)d_in[4];
    const float* bk = (const float*)d_in[5];
    const float* Wv = (const float*)d_in[6];
    const float* bv = (const float*)d_in[7];
    float* out = (float*)d_out;

    float* ws = (float*)d_ws;
    const size_t plane = (size_t)BATCH * NTOK * CDIM;   // 4,718,592 floats
    float* Q = ws;
    float* K = ws + plane;
    float* V = ws + 2 * plane;

    dim3 pgrid(NTOK / 64, CDIM / 64, BATCH * 3);
    proj_kernel<<<pgrid, dim3(256), 0, stream>>>(x1, x2, Wq, bq, Wk, bk, Wv, bv,
                                                 Q, K, V);

    dim3 agrid(NTOK / 32, BATCH);
    attn_kernel<<<agrid, dim3(256), 0, stream>>>(Q, K, V, out);
}

// Round 2
// 418.992 us; speedup vs baseline: 2.8866x; 2.8866x over previous
//
#include <hip/hip_runtime.h>
#include <cfloat>
#include <cstddef>

#define BATCH 8
#define CDIM  256
#define NTOK  2304   // 48*48

typedef float    f32x4 __attribute__((ext_vector_type(4)));
typedef _Float16 f16x8 __attribute__((ext_vector_type(8)));
typedef _Float16 f16x4 __attribute__((ext_vector_type(4)));

#define MFMA16(a, b, c) __builtin_amdgcn_mfma_f32_16x16x32_f16(a, b, c, 0, 0, 0)

// ---------------------------------------------------------------------------
// Projection (fp32 math, fp16 store):
// mode 0: Q from x1 -> [B,N,C] fp16
// mode 1: K from x2 -> [B,N,C] fp16
// mode 2: V from x2 -> [B,C,N] fp16
// ---------------------------------------------------------------------------
__global__ __launch_bounds__(256) void proj_kernel(
    const float* __restrict__ x1, const float* __restrict__ x2,
    const float* __restrict__ Wq, const float* __restrict__ bq,
    const float* __restrict__ Wk, const float* __restrict__ bk,
    const float* __restrict__ Wv, const float* __restrict__ bv,
    _Float16* __restrict__ Qo, _Float16* __restrict__ Ko, _Float16* __restrict__ Vo)
{
    const int tid = threadIdx.x;
    const int tx = tid & 15, ty = tid >> 4;
    const int n0 = blockIdx.x * 64;
    const int o0 = blockIdx.y * 64;
    const int bz = blockIdx.z;
    const int b = bz / 3, mode = bz % 3;

    const float* X    = (mode == 0) ? x1 : x2;
    const float* W    = (mode == 0) ? Wq : (mode == 1) ? Wk : Wv;
    const float* bias = (mode == 0) ? bq : (mode == 1) ? bk : bv;
    _Float16*    OUT  = (mode == 0) ? Qo : (mode == 1) ? Ko : Vo;

    __shared__ float Ws[16][68];
    __shared__ float Xs[16][64];

    float acc[4][4];
#pragma unroll
    for (int i = 0; i < 4; ++i)
#pragma unroll
        for (int j = 0; j < 4; ++j) acc[i][j] = 0.f;

    for (int c0 = 0; c0 < CDIM; c0 += 16) {
        __syncthreads();
#pragma unroll
        for (int it = 0; it < 4; ++it) {
            int e = tid + it * 256;
            Ws[e & 15][e >> 4] = W[(o0 + (e >> 4)) * CDIM + c0 + (e & 15)];
        }
#pragma unroll
        for (int it = 0; it < 4; ++it) {
            int e = tid + it * 256;
            Xs[e >> 6][e & 63] =
                X[(size_t)(b * CDIM + c0 + (e >> 6)) * NTOK + n0 + (e & 63)];
        }
        __syncthreads();
#pragma unroll
        for (int kc = 0; kc < 16; ++kc) {
            float4 a  = *(const float4*)&Ws[kc][ty * 4];
            float4 xv = *(const float4*)&Xs[kc][tx * 4];
            acc[0][0] = fmaf(a.x, xv.x, acc[0][0]);
            acc[0][1] = fmaf(a.x, xv.y, acc[0][1]);
            acc[0][2] = fmaf(a.x, xv.z, acc[0][2]);
            acc[0][3] = fmaf(a.x, xv.w, acc[0][3]);
            acc[1][0] = fmaf(a.y, xv.x, acc[1][0]);
            acc[1][1] = fmaf(a.y, xv.y, acc[1][1]);
            acc[1][2] = fmaf(a.y, xv.z, acc[1][2]);
            acc[1][3] = fmaf(a.y, xv.w, acc[1][3]);
            acc[2][0] = fmaf(a.z, xv.x, acc[2][0]);
            acc[2][1] = fmaf(a.z, xv.y, acc[2][1]);
            acc[2][2] = fmaf(a.z, xv.z, acc[2][2]);
            acc[2][3] = fmaf(a.z, xv.w, acc[2][3]);
            acc[3][0] = fmaf(a.w, xv.x, acc[3][0]);
            acc[3][1] = fmaf(a.w, xv.y, acc[3][1]);
            acc[3][2] = fmaf(a.w, xv.z, acc[3][2]);
            acc[3][3] = fmaf(a.w, xv.w, acc[3][3]);
        }
    }

    if (mode == 2) {
        // V: [B, C, N]
#pragma unroll
        for (int i = 0; i < 4; ++i) {
            float bb = bias[o0 + ty * 4 + i];
            f16x4 v = { (_Float16)(acc[i][0] + bb), (_Float16)(acc[i][1] + bb),
                        (_Float16)(acc[i][2] + bb), (_Float16)(acc[i][3] + bb) };
            *(f16x4*)&OUT[(size_t)(b * CDIM + o0 + ty * 4 + i) * NTOK + n0 + tx * 4] = v;
        }
    } else {
        // Q / K: [B, N, C]
        float b0 = bias[o0 + ty * 4 + 0];
        float b1 = bias[o0 + ty * 4 + 1];
        float b2 = bias[o0 + ty * 4 + 2];
        float b3 = bias[o0 + ty * 4 + 3];
#pragma unroll
        for (int j = 0; j < 4; ++j) {
            f16x4 v = { (_Float16)(acc[0][j] + b0), (_Float16)(acc[1][j] + b1),
                        (_Float16)(acc[2][j] + b2), (_Float16)(acc[3][j] + b3) };
            *(f16x4*)&OUT[(size_t)(b * NTOK + n0 + tx * 4 + j) * CDIM + o0 + ty * 4] = v;
        }
    }
}

// ---------------------------------------------------------------------------
// MFMA flash attention. 4 waves x 16 q-rows = 64 q-rows per block, KVBLK=64.
// Q,K: [B,N,C] fp16; Vt: [B,C,N] fp16; out: [B,C,N] fp32.
// Fragment conventions (mfma_f32_16x16x32_f16):
//   A: row = lane&15, k = (lane>>4)*8 + e      (consistent k-mapping A<->B)
//   B: col = lane&15, k = (lane>>4)*8 + e
//   D: col = lane&15, row = (lane>>4)*4 + reg  (HW-verified, m89)
// LDS swizzle (G4): 16B-slot ^= (row & 7) -> conflict-free b128 read & write.
// ---------------------------------------------------------------------------
__global__ __launch_bounds__(256, 2) void attn_mfma(
    const _Float16* __restrict__ Q, const _Float16* __restrict__ K,
    const _Float16* __restrict__ Vt, float* __restrict__ out)
{
    const int tid  = threadIdx.x;
    const int lane = tid & 63;
    const int w    = tid >> 6;
    const int b    = blockIdx.y;
    const int n0   = blockIdx.x * 64;
    const int l15  = lane & 15, l4 = lane >> 4;

    __shared__ _Float16 Vl[256 * 64];   // V tile, [c][j], swizzled
    __shared__ _Float16 Pl[64 * 64];    // P tile, [i][j], swizzled, wave-sliced

    // ---- Q fragments: 16 rows x 256 c in registers (8 k-chunks) ----
    f16x8 qa[8];
    {
        const _Float16* qbase =
            Q + ((size_t)b * NTOK + n0 + 16 * w + l15) * CDIM + l4 * 8;
#pragma unroll
        for (int kk = 0; kk < 8; ++kk)
            qa[kk] = *(const f16x8*)(qbase + kk * 32);
    }

    f32x4 acc[16];
#pragma unroll
    for (int ct = 0; ct < 16; ++ct) acc[ct] = (f32x4){0.f, 0.f, 0.f, 0.f};
    float m[4] = {-FLT_MAX, -FLT_MAX, -FLT_MAX, -FLT_MAX};
    float l[4] = {0.f, 0.f, 0.f, 0.f};

    for (int jt = 0; jt < NTOK / 64; ++jt) {
        const int j0 = jt * 64;
        __syncthreads();   // all waves done with previous V tile

        // ---- stage V tile [256 c][64 j] -> LDS (swizzled), coalesced ----
        {
            const _Float16* vsrc = Vt + (size_t)b * CDIM * NTOK + j0;
#pragma unroll
            for (int i = 0; i < 8; ++i) {
                int r  = i * 32 + (tid >> 3);
                int cb = tid & 7;
                f16x8 v = *(const f16x8*)(vsrc + (size_t)r * NTOK + cb * 8);
                int slot = cb ^ (r & 7);
                *(f16x8*)&Vl[r * 64 + slot * 8] = v;
            }
        }
        __syncthreads();

        // ---- QK^T: S[16 i][64 j], K fragments direct from global (L2) ----
        f32x4 s[4];
#pragma unroll
        for (int nt = 0; nt < 4; ++nt) {
            const _Float16* kbase =
                K + ((size_t)b * NTOK + j0 + nt * 16 + l15) * CDIM + l4 * 8;
            f16x8 kf[8];
#pragma unroll
            for (int kk = 0; kk < 8; ++kk)
                kf[kk] = *(const f16x8*)(kbase + kk * 32);
            f32x4 sv = (f32x4){0.f, 0.f, 0.f, 0.f};
#pragma unroll
            for (int kk = 0; kk < 8; ++kk)
                sv = MFMA16(qa[kk], kf[kk], sv);
            s[nt] = sv;
        }

        // ---- online softmax (lane-local rows: i = 4*l4 + reg) ----
#pragma unroll
        for (int reg = 0; reg < 4; ++reg) {
            float pm = fmaxf(fmaxf(s[0][reg], s[1][reg]),
                             fmaxf(s[2][reg], s[3][reg]));
            pm = fmaxf(pm, __shfl_xor(pm, 1));
            pm = fmaxf(pm, __shfl_xor(pm, 2));
            pm = fmaxf(pm, __shfl_xor(pm, 4));
            pm = fmaxf(pm, __shfl_xor(pm, 8));
            if (pm > m[reg] + 8.f) {           // defer-max (T13, THR=8)
                float sc = __expf(m[reg] - pm);
                m[reg] = pm;
                l[reg] *= sc;
#pragma unroll
                for (int ct = 0; ct < 16; ++ct) acc[ct][reg] *= sc;
            }
            float ps = 0.f;
            const int row = 16 * w + 4 * l4 + reg;
#pragma unroll
            for (int nt = 0; nt < 4; ++nt) {
                float p = __expf(s[nt][reg] - m[reg]);
                ps += p;
                int j = nt * 16 + l15;
                int slot = (j >> 3) ^ (row & 7);
                Pl[row * 64 + slot * 8 + (j & 7)] = (_Float16)p;
            }
            ps += __shfl_xor(ps, 1);
            ps += __shfl_xor(ps, 2);
            ps += __shfl_xor(ps, 4);
            ps += __shfl_xor(ps, 8);
            l[reg] += ps;
        }

        // cross-lane dependency through Pl within the wave: drain LDS writes
        asm volatile("s_waitcnt lgkmcnt(0)" ::: "memory");
        __builtin_amdgcn_sched_barrier(0);

        // ---- PV: acc[16 i][256 c] += P[16 i][64 j] * V[64 j][256 c] ----
        f16x8 pa[2];
#pragma unroll
        for (int kc = 0; kc < 2; ++kc) {
            int row = 16 * w + l15;
            int slot = (kc * 4 + l4) ^ (row & 7);
            pa[kc] = *(const f16x8*)&Pl[row * 64 + slot * 8];
        }
#pragma unroll
        for (int ct = 0; ct < 16; ++ct) {
#pragma unroll
            for (int kc = 0; kc < 2; ++kc) {
                int r = ct * 16 + l15;
                int slot = (kc * 4 + l4) ^ (r & 7);
                f16x8 vb = *(const f16x8*)&Vl[r * 64 + slot * 8];
                acc[ct] = MFMA16(pa[kc], vb, acc[ct]);
            }
        }
    }

    // ---- epilogue: normalize, store out[B,C,N] fp32 ----
#pragma unroll
    for (int reg = 0; reg < 4; ++reg) {
        float inv = 1.f / l[reg];
        int n = n0 + 16 * w + 4 * l4 + reg;
#pragma unroll
        for (int ct = 0; ct < 16; ++ct) {
            out[((size_t)b * CDIM + ct * 16 + l15) * NTOK + n] = acc[ct][reg] * inv;
        }
    }
}

// ---------------------------------------------------------------------------
extern "C" void kernel_launch(void* const* d_in, const int* in_sizes, int n_in,
                              void* d_out, int out_size, void* d_ws, size_t ws_size,
                              hipStream_t stream)
{
    const float* x1 = (const float*)d_in[0];
    const float* x2 = (const float*)d_in[1];
    const float* Wq = (const float*)d_in[2];
    const float* bq = (const float*)d_in[3];
    const float* Wk = (const float*)d_in[4];
    const float* bk = (const float*)d_in[5];
    const float* Wv = (const float*)d_in[6];
    const float* bv = (const float*)d_in[7];
    float* out = (float*)d_out;

    _Float16* ws = (_Float16*)d_ws;
    const size_t plane = (size_t)BATCH * NTOK * CDIM;   // 4,718,592 elements
    _Float16* Q  = ws;              // [B,N,C]
    _Float16* K  = ws + plane;      // [B,N,C]
    _Float16* Vt = ws + 2 * plane;  // [B,C,N]

    dim3 pgrid(NTOK / 64, CDIM / 64, BATCH * 3);
    proj_kernel<<<pgrid, dim3(256), 0, stream>>>(x1, x2, Wq, bq, Wk, bk, Wv, bv,
                                                 Q, K, Vt);

    dim3 agrid(NTOK / 64, BATCH);
    attn_mfma<<<agrid, dim3(256), 0, stream>>>(Q, K, Vt, out);
}